// Round 2
// baseline (138.619 us; speedup 1.0000x reference)
//
#include <hip/hip_runtime.h>
#include <stdint.h>

typedef unsigned short u16;
typedef short bf16x8 __attribute__((ext_vector_type(8)));
typedef float f32x4 __attribute__((ext_vector_type(4)));

#define PI_F 3.14159265358979323846f
#define NSAMP 512000
#define MROWS 16000
#define KDIM 1024
#define NKOUT 512

__device__ __forceinline__ u16 f2bf(float f) {
  uint32_t x = __float_as_uint(f);
  return (u16)((x + 0x7fffu + ((x >> 16) & 1u)) >> 16);  // RNE
}
__device__ __forceinline__ float bf2f(u16 u) {
  return __uint_as_float(((uint32_t)u) << 16);
}

// Basis, transposed: Bt[col k=0..511][n=0..1023], split into bf16 hi+lo.
// Bt[k][n] = (1/16) * sin(pi*(2n+1)/2048) * cos(pi*((2n+513)(2k+1) mod 4096)/2048)
__global__ void build_basis(u16* __restrict__ bt_hi, u16* __restrict__ bt_lo) {
  int idx = blockIdx.x * 256 + threadIdx.x;  // 512*1024 elements
  int k = idx >> 10;
  int n = idx & 1023;
  float w = sinf(PI_F * (float)(2 * n + 1) / 2048.0f);
  int P = ((2 * n + 513) * (2 * k + 1)) & 4095;  // exact phase mod 2 (in pi units *2048)
  float c = cosf(PI_F * (float)P / 2048.0f);
  float v = 0.0625f * w * c;
  u16 hi = f2bf(v);
  bt_hi[idx] = hi;
  bt_lo[idx] = f2bf(v - bf2f(hi));
}

__device__ __forceinline__ void gl_lds16(const u16* g, u16* l) {
  __builtin_amdgcn_global_load_lds(
      (const __attribute__((address_space(1))) uint32_t*)g,
      (__attribute__((address_space(3))) uint32_t*)l, 16, 0, 0);
}

// GEMM: out[16000][512] = X[16000][1024] * B[1024][512]
// X[m][n] = audio[b][l*512+n-256] (zero-padded), m = b*1000+l, window folded into B.
// Tile 128x128, BK=32, 256 threads (4 waves, 2x2, each wave 64x64 = 4x4 frags of 16x16).
// LDS layouts [row|col][32k] bf16, 16B chunk at (r, slot) stored at r*64 + (slot^((r>>1)&3))*16.
__global__ __launch_bounds__(256, 2) void mdct_mfma(
    const float* __restrict__ audio,
    const u16* __restrict__ bt_hi,
    const u16* __restrict__ bt_lo,
    float* __restrict__ out) {
  __shared__ u16 lds[16384];  // 32KB: Ahi, Alo, Bhi, Blo (8KB each)
  u16* Ahi = lds;
  u16* Alo = lds + 4096;
  u16* Bhi = lds + 8192;
  u16* Blo = lds + 12288;

  const int tid = threadIdx.x;
  const int lane = tid & 63;
  const int wid = tid >> 6;
  const int wr = wid >> 1;
  const int wc = wid & 1;

  const int m0 = ((int)blockIdx.x >> 2) * 128;  // 125 row tiles
  const int n0 = ((int)blockIdx.x & 3) * 128;   // 4 col tiles

  // Staging precompute: chunk c = tid + 256*s covers (row=c/4, slot=c%4), 8 elems.
  const float* aptr[2];
  int at0[2], awoff[2], beoff[2];
#pragma unroll
  for (int s = 0; s < 2; ++s) {
    int c = tid + 256 * s;
    int row = c >> 2, slot = c & 3;
    int m = m0 + row;
    int b = m / 1000;
    int l = m - b * 1000;
    aptr[s] = audio + (size_t)b * NSAMP;
    at0[s] = l * 512 + slot * 8 - 256;  // multiple of 8 -> no straddle at 0 / NSAMP
    awoff[s] = row * 64 + ((slot ^ ((row >> 1) & 3)) << 4);
    int srcslot = slot ^ ((row >> 1) & 3);  // inverse swizzle on the SOURCE (rule #21)
    beoff[s] = (n0 + row) * KDIM + srcslot * 8;
  }

  // Fragment read offsets (constant over K loop)
  int aoff[4], boff[4];
#pragma unroll
  for (int mi = 0; mi < 4; ++mi) {
    int row = wr * 64 + mi * 16 + (lane & 15);
    aoff[mi] = row * 64 + (((lane >> 4) ^ ((row >> 1) & 3)) << 4);
  }
#pragma unroll
  for (int ni = 0; ni < 4; ++ni) {
    int col = wc * 64 + ni * 16 + (lane & 15);
    boff[ni] = col * 64 + (((lane >> 4) ^ ((col >> 1) & 3)) << 4);
  }

  f32x4 acc[4][4];
#pragma unroll
  for (int mi = 0; mi < 4; ++mi)
#pragma unroll
    for (int ni = 0; ni < 4; ++ni)
      acc[mi][ni] = (f32x4){0.f, 0.f, 0.f, 0.f};

  for (int kk = 0; kk < KDIM; kk += 32) {
    __syncthreads();  // prev-iter frag reads done before overwrite

    // B tiles: async global->LDS, linear dest (wave-uniform base + lane*16)
#pragma unroll
    for (int s = 0; s < 2; ++s) {
      int i8 = (tid + 256 * s) * 8;
      gl_lds16(bt_hi + beoff[s] + kk, Bhi + i8);
      gl_lds16(bt_lo + beoff[s] + kk, Blo + i8);
    }

    // A tiles: fp32 load -> bf16 hi/lo split -> swizzled ds_write_b128
#pragma unroll
    for (int s = 0; s < 2; ++s) {
      int t = at0[s] + kk;
      float4 x01 = make_float4(0.f, 0.f, 0.f, 0.f);
      float4 x23 = x01;
      if ((unsigned)t < (unsigned)NSAMP) {
        x01 = *(const float4*)(aptr[s] + t);
        x23 = *(const float4*)(aptr[s] + t + 4);
      }
      float xs[8] = {x01.x, x01.y, x01.z, x01.w, x23.x, x23.y, x23.z, x23.w};
      bf16x8 vh, vl;
#pragma unroll
      for (int j = 0; j < 8; ++j) {
        u16 h = f2bf(xs[j]);
        vh[j] = (short)h;
        vl[j] = (short)f2bf(xs[j] - bf2f(h));
      }
      *(bf16x8*)((char*)Ahi + awoff[s]) = vh;
      *(bf16x8*)((char*)Alo + awoff[s]) = vl;
    }

    __syncthreads();

    bf16x8 ah[4], al[4], bh[4], bl[4];
#pragma unroll
    for (int mi = 0; mi < 4; ++mi) {
      ah[mi] = *(const bf16x8*)((const char*)Ahi + aoff[mi]);
      al[mi] = *(const bf16x8*)((const char*)Alo + aoff[mi]);
    }
#pragma unroll
    for (int ni = 0; ni < 4; ++ni) {
      bh[ni] = *(const bf16x8*)((const char*)Bhi + boff[ni]);
      bl[ni] = *(const bf16x8*)((const char*)Blo + boff[ni]);
    }
#pragma unroll
    for (int mi = 0; mi < 4; ++mi)
#pragma unroll
      for (int ni = 0; ni < 4; ++ni) {
        acc[mi][ni] = __builtin_amdgcn_mfma_f32_16x16x32_bf16(ah[mi], bh[ni], acc[mi][ni], 0, 0, 0);
        acc[mi][ni] = __builtin_amdgcn_mfma_f32_16x16x32_bf16(ah[mi], bl[ni], acc[mi][ni], 0, 0, 0);
        acc[mi][ni] = __builtin_amdgcn_mfma_f32_16x16x32_bf16(al[mi], bh[ni], acc[mi][ni], 0, 0, 0);
      }
  }

  // Epilogue: C/D layout col=lane&15, row=(lane>>4)*4+reg (m89-verified)
#pragma unroll
  for (int mi = 0; mi < 4; ++mi) {
    int row0 = m0 + wr * 64 + mi * 16 + ((lane >> 4) << 2);
#pragma unroll
    for (int ni = 0; ni < 4; ++ni) {
      int col = n0 + wc * 64 + ni * 16 + (lane & 15);
      float* p = out + (size_t)row0 * NKOUT + col;
      f32x4 v = acc[mi][ni];
      p[0] = v[0];
      p[NKOUT] = v[1];
      p[2 * NKOUT] = v[2];
      p[3 * NKOUT] = v[3];
    }
  }
}

// Correct-but-slow fallback if workspace is unexpectedly small.
__global__ void mdct_naive(const float* __restrict__ audio, float* __restrict__ out) {
  int idx = blockIdx.x * 256 + threadIdx.x;
  if (idx >= MROWS * NKOUT) return;
  int k = idx & (NKOUT - 1);
  int m = idx >> 9;
  int b = m / 1000, l = m - b * 1000;
  const float* a = audio + (size_t)b * NSAMP;
  float s = 0.f;
  for (int n = 0; n < KDIM; ++n) {
    int t = l * 512 + n - 256;
    float x = ((unsigned)t < (unsigned)NSAMP) ? a[t] : 0.f;
    float w = sinf(PI_F * (float)(2 * n + 1) / 2048.0f);
    int P = ((2 * n + 513) * (2 * k + 1)) & 4095;
    s += x * w * cosf(PI_F * (float)P / 2048.0f);
  }
  out[idx] = 0.0625f * s;
}

extern "C" void kernel_launch(void* const* d_in, const int* in_sizes, int n_in,
                              void* d_out, int out_size, void* d_ws, size_t ws_size,
                              hipStream_t stream) {
  const float* audio = (const float*)d_in[0];
  float* out = (float*)d_out;
  size_t need = (size_t)NKOUT * KDIM * 2 * sizeof(u16);  // 2 MB
  if (d_ws != nullptr && ws_size >= need) {
    u16* bt_hi = (u16*)d_ws;
    u16* bt_lo = bt_hi + (size_t)NKOUT * KDIM;
    build_basis<<<(NKOUT * KDIM) / 256, 256, 0, stream>>>(bt_hi, bt_lo);
    mdct_mfma<<<(MROWS / 128) * (NKOUT / 128), 256, 0, stream>>>(audio, bt_hi, bt_lo, out);
  } else {
    mdct_naive<<<(MROWS * NKOUT + 255) / 256, 256, 0, stream>>>(audio, out);
  }
}

// Round 3
// 116.345 us; speedup vs baseline: 1.1914x; 1.1914x over previous
//
#include <hip/hip_runtime.h>
#include <stdint.h>

typedef unsigned short u16;
typedef short bf16x8 __attribute__((ext_vector_type(8)));
typedef float f32x4 __attribute__((ext_vector_type(4)));

#define PI_F 3.14159265358979323846f
#define NSAMP 512000
#define MROWS 16000
#define K2 512     // folded K
#define NKOUT 512
#define BK 64
#define NBLK 500

__device__ __forceinline__ u16 f2bf(float f) {
  uint32_t x = __float_as_uint(f);
  return (u16)((x + 0x7fffu + ((x >> 16) & 1u)) >> 16);  // RNE
}
__device__ __forceinline__ float bf2f(u16 u) {
  return __uint_as_float(((uint32_t)u) << 16);
}

// Folded basis Bf[k][m], k,m in [0,512). theta = pi*((2n+513)(2k+1) mod 4096)/2048, n=m&255.
// m<256: cos(theta); m>=256: -(-1)^k sin(theta). Scale 1/16 folded in. Split bf16 hi+lo.
__global__ void build_basis(u16* __restrict__ bt_hi, u16* __restrict__ bt_lo) {
  int idx = blockIdx.x * 256 + threadIdx.x;  // 512*512
  int k = idx >> 9, m = idx & 511;
  int n = m & 255;
  int P = ((2 * n + 513) * (2 * k + 1)) & 4095;
  float ang = PI_F * (float)P / 2048.0f;
  float v = (m < 256) ? cosf(ang) : ((k & 1) ? sinf(ang) : -sinf(ang));
  v *= 0.0625f;
  u16 hi = f2bf(v);
  bt_hi[idx] = hi;
  bt_lo[idx] = f2bf(v - bf2f(hi));
}

// Window fold tables: phi = pi*(2n+1)/2048, n in [0,256)
__global__ void build_window(float* __restrict__ wsin, float* __restrict__ wcos) {
  int n = threadIdx.x;
  float ph = PI_F * (float)(2 * n + 1) / 2048.0f;
  wsin[n] = sinf(ph);
  wcos[n] = cosf(ph);
}

__device__ __forceinline__ void gl_lds16(const u16* g, u16* l) {
  __builtin_amdgcn_global_load_lds(
      (const __attribute__((address_space(1))) uint32_t*)g,
      (__attribute__((address_space(3))) uint32_t*)l, 16, 0, 0);
}

// out[16000][512] = Af[16000][512] * Bf[512][512]^T-stored, where
// Af[m][n<256] = u_n = x[n]*sin(phi_n) - x[511-n]*cos(phi_n)
// Af[m][256+n]  = v_n = x[512+n]*cos(phi_n) + x[1023-n]*sin(phi_n)   (frame offsets, zero-padded)
// Tile 128x128, BK=64, 256 threads (4 waves 2x2, 64x64 each). LDS row = 64 el (128B),
// 8 slots of 16B, XOR-swizzled: slot' = slot ^ (row&7).
__global__ __launch_bounds__(256, 2) void mdct_mfma(
    const float* __restrict__ audio,
    const u16* __restrict__ bt_hi, const u16* __restrict__ bt_lo,
    const float* __restrict__ wsin_g, const float* __restrict__ wcos_g,
    float* __restrict__ out) {
  __shared__ u16 Ahi[8192], Alo[8192], Bhi[8192], Blo[8192];  // 16KB each
  __shared__ float Wsin[256], Wcos[256];

  const int tid = threadIdx.x;
  const int lane = tid & 63;
  const int wid = tid >> 6;
  const int wr = wid >> 1, wcol = wid & 1;

  // Bijective XCD swizzle (m204): 500 = 8*62+4 -> xcd<4 gets 63 logical ids.
  int orig = (int)blockIdx.x;
  int xcd = orig & 7, bidx = orig >> 3;
  int wgid = (xcd < 4 ? xcd * 63 : 252 + (xcd - 4) * 62) + bidx;
  const int m0 = (wgid >> 2) * 128;
  const int n0 = (wgid & 3) * 128;

  // Window tables -> LDS (ordered before first use by loop-top barrier)
  if (tid < 64)
    ((float4*)Wsin)[tid] = ((const float4*)wsin_g)[tid];
  else if (tid < 128)
    ((float4*)Wcos)[tid - 64] = ((const float4*)wcos_g)[tid - 64];

  // Per-s staging constants: chunk c = tid+256s -> (row=c>>3, slot=c&7), 8 elems.
  const float* aptr[4];
  int base_[4], sl8_[4], awoff_[4], beoff_[4], bdst_[4];
#pragma unroll
  for (int s = 0; s < 4; ++s) {
    int c = tid + 256 * s;
    int row = c >> 3, slot = c & 7;
    int m = m0 + row;
    int b = m / 1000, l = m - b * 1000;
    aptr[s] = audio + (size_t)b * NSAMP;
    base_[s] = l * 512 - 256;  // frame start in audio coords
    sl8_[s] = slot * 8;
    int sw = slot ^ (row & 7);
    awoff_[s] = row * 128 + sw * 16;       // byte offset, swizzled dest (ds_write)
    beoff_[s] = (n0 + row) * K2 + sw * 8;  // element offset, pre-swizzled SOURCE (rule #21)
    bdst_[s] = c * 8;                      // element offset, linear dest (gl_lds)
  }

  f32x4 acc[4][4];
#pragma unroll
  for (int mi = 0; mi < 4; ++mi)
#pragma unroll
    for (int ni = 0; ni < 4; ++ni)
      acc[mi][ni] = (f32x4){0.f, 0.f, 0.f, 0.f};

  for (int kk = 0; kk < K2; kk += BK) {
    __syncthreads();  // prev-iter frag reads done; also orders Wsin/Wcos writes (kk=0)

    // B: async global->LDS, linear dest
#pragma unroll
    for (int s = 0; s < 4; ++s) {
      gl_lds16(bt_hi + beoff_[s] + kk, Bhi + bdst_[s]);
      gl_lds16(bt_lo + beoff_[s] + kk, Blo + bdst_[s]);
    }

    // A: load fwd+rev regions, window-fold, split hi/lo, swizzled ds_write.
    // kk<256 -> all u-chunks; kk>=256 -> all v-chunks (wave-uniform).
    const bool isU = (kk < 256);
#pragma unroll
    for (int s = 0; s < 4; ++s) {
      int n0c = kk + sl8_[s] - (isU ? 0 : 256);  // [0,256), mult of 8
      int tf = base_[s] + (isU ? n0c : 512 + n0c);
      int tr = base_[s] + (isU ? 504 - n0c : 1016 - n0c);
      float4 f0 = make_float4(0.f, 0.f, 0.f, 0.f), f1 = f0, r0 = f0, r1 = f0;
      if ((unsigned)tf < (unsigned)NSAMP) {  // only l=0 u-fwd can be OOB
        f0 = *(const float4*)(aptr[s] + tf);
        f1 = *(const float4*)(aptr[s] + tf + 4);
      }
      if ((unsigned)tr < (unsigned)NSAMP) {  // only l=999 v-rev can be OOB
        r0 = *(const float4*)(aptr[s] + tr);
        r1 = *(const float4*)(aptr[s] + tr + 4);
      }
      float4 s0 = *(const float4*)&Wsin[n0c], s1 = *(const float4*)&Wsin[n0c + 4];
      float4 c0 = *(const float4*)&Wcos[n0c], c1 = *(const float4*)&Wcos[n0c + 4];
      float xf[8] = {f0.x, f0.y, f0.z, f0.w, f1.x, f1.y, f1.z, f1.w};
      float xr[8] = {r0.x, r0.y, r0.z, r0.w, r1.x, r1.y, r1.z, r1.w};
      float sw_[8] = {s0.x, s0.y, s0.z, s0.w, s1.x, s1.y, s1.z, s1.w};
      float cw_[8] = {c0.x, c0.y, c0.z, c0.w, c1.x, c1.y, c1.z, c1.w};
      bf16x8 vh, vl;
#pragma unroll
      for (int j = 0; j < 8; ++j) {
        // rev loads ascend in addr; addr tr+i corresponds to j=7-i
        float uv = isU ? (xf[j] * sw_[j] - xr[7 - j] * cw_[j])
                       : (xf[j] * cw_[j] + xr[7 - j] * sw_[j]);
        u16 h = f2bf(uv);
        vh[j] = (short)h;
        vl[j] = (short)f2bf(uv - bf2f(h));
      }
      *(bf16x8*)((char*)Ahi + awoff_[s]) = vh;
      *(bf16x8*)((char*)Alo + awoff_[s]) = vl;
    }

    __syncthreads();

#pragma unroll
    for (int kb = 0; kb < 2; ++kb) {
      bf16x8 ah[4], al[4], bh[4], bl[4];
#pragma unroll
      for (int mi = 0; mi < 4; ++mi) {
        int row = wr * 64 + mi * 16 + (lane & 15);
        int off = row * 128 + ((((kb << 2) | (lane >> 4)) ^ (row & 7)) << 4);
        ah[mi] = *(const bf16x8*)((const char*)Ahi + off);
        al[mi] = *(const bf16x8*)((const char*)Alo + off);
      }
#pragma unroll
      for (int ni = 0; ni < 4; ++ni) {
        int col = wcol * 64 + ni * 16 + (lane & 15);
        int off = col * 128 + ((((kb << 2) | (lane >> 4)) ^ (col & 7)) << 4);
        bh[ni] = *(const bf16x8*)((const char*)Bhi + off);
        bl[ni] = *(const bf16x8*)((const char*)Blo + off);
      }
#pragma unroll
      for (int mi = 0; mi < 4; ++mi)
#pragma unroll
        for (int ni = 0; ni < 4; ++ni) {
          acc[mi][ni] = __builtin_amdgcn_mfma_f32_16x16x32_bf16(ah[mi], bh[ni], acc[mi][ni], 0, 0, 0);
          acc[mi][ni] = __builtin_amdgcn_mfma_f32_16x16x32_bf16(ah[mi], bl[ni], acc[mi][ni], 0, 0, 0);
          acc[mi][ni] = __builtin_amdgcn_mfma_f32_16x16x32_bf16(al[mi], bh[ni], acc[mi][ni], 0, 0, 0);
        }
    }
  }

  // Epilogue: C/D layout col=lane&15, row=(lane>>4)*4+reg (m89-verified, passed r2)
#pragma unroll
  for (int mi = 0; mi < 4; ++mi) {
    int row0 = m0 + wr * 64 + mi * 16 + ((lane >> 4) << 2);
#pragma unroll
    for (int ni = 0; ni < 4; ++ni) {
      int col = n0 + wcol * 64 + ni * 16 + (lane & 15);
      float* p = out + (size_t)row0 * NKOUT + col;
      f32x4 v = acc[mi][ni];
      p[0] = v[0];
      p[NKOUT] = v[1];
      p[2 * NKOUT] = v[2];
      p[3 * NKOUT] = v[3];
    }
  }
}

// Correct-but-slow fallback (unfolded, fp32-exact) if workspace too small.
__global__ void mdct_naive(const float* __restrict__ audio, float* __restrict__ out) {
  int idx = blockIdx.x * 256 + threadIdx.x;
  if (idx >= MROWS * NKOUT) return;
  int k = idx & (NKOUT - 1);
  int m = idx >> 9;
  int b = m / 1000, l = m - b * 1000;
  const float* a = audio + (size_t)b * NSAMP;
  float s = 0.f;
  for (int n = 0; n < 1024; ++n) {
    int t = l * 512 + n - 256;
    float x = ((unsigned)t < (unsigned)NSAMP) ? a[t] : 0.f;
    float w = sinf(PI_F * (float)(2 * n + 1) / 2048.0f);
    int P = ((2 * n + 513) * (2 * k + 1)) & 4095;
    s += x * w * cosf(PI_F * (float)P / 2048.0f);
  }
  out[idx] = 0.0625f * s;
}

extern "C" void kernel_launch(void* const* d_in, const int* in_sizes, int n_in,
                              void* d_out, int out_size, void* d_ws, size_t ws_size,
                              hipStream_t stream) {
  const float* audio = (const float*)d_in[0];
  float* out = (float*)d_out;
  size_t tbl = (size_t)NKOUT * K2;                       // 262144 elems
  size_t need = tbl * 2 * sizeof(u16) + 512 * sizeof(float);  // ~1.03 MB
  if (d_ws != nullptr && ws_size >= need) {
    u16* bt_hi = (u16*)d_ws;
    u16* bt_lo = bt_hi + tbl;
    float* wsin = (float*)(bt_lo + tbl);
    float* wcos = wsin + 256;
    build_basis<<<(NKOUT * K2) / 256, 256, 0, stream>>>(bt_hi, bt_lo);
    build_window<<<1, 256, 0, stream>>>(wsin, wcos);
    mdct_mfma<<<NBLK, 256, 0, stream>>>(audio, bt_hi, bt_lo, wsin, wcos, out);
  } else {
    mdct_naive<<<(MROWS * NKOUT + 255) / 256, 256, 0, stream>>>(audio, out);
  }
}